// Round 1
// baseline (177.892 us; speedup 1.0000x reference)
//
#include <hip/hip_runtime.h>

// out[p][f] = sum_s x[p][s] * K[s][f];  P = 393,216, K 64x64 fp32.
//
// R6: R5 counters (MfmaUtil 5.9, VALUBusy 17.4, hbm 31.8%, Occ 28.6) say the
// 59.4us MFMA kernel is LATENCY-bound, not pipe-bound. Old structure: 6144
// tiny blocks, each a serial chain {global->LDS, sync, K-build, sync, 24
// MFMA, store} -- never enough independent VMEM in flight. Restructure as a
// barrier-free streaming kernel:
//   * K hi/lo B-frags built once per block (LDS), hoisted to 64 VGPRs;
//     main loop has ZERO LDS traffic (bank-conflict counter -> ~0).
//   * A-frags loaded DIRECTLY global->reg: the frag pattern (16 patches x
//     64 floats, per-lane dwordx4 at p*256+quad*32) uses every 64B granule
//     fully -- the LDS x round-trip was pure overhead.
//   * grid-stride, 3 tiles/wave; next tile's 4 dwordx4 prefetched while the
//     current tile converts + 24 MFMAs + 16 stores. No barrier in the loop.
// Numerics unchanged: 3-term bf16 hi/lo split, verified absmax 0.03125.
// Prediction: 59.4 -> ~30-34us (151MB HBM @ ~5+ TB/s), hbm_pct 32->60+,
// MfmaUtil ~11, VALUBusy ~30, bank-conflicts ~0, FETCH/WRITE unchanged.

#define THREADS 256
#define WPB     4          // waves per block
#define TPW     3          // tiles per wave (24576 wave-tiles / 8192 waves)

typedef __attribute__((ext_vector_type(8))) short bf16x8;
typedef __attribute__((ext_vector_type(4))) float f32x4;

static __device__ __forceinline__ unsigned short bf16_rne(float f) {
    unsigned int u = __float_as_uint(f);
    u += 0x7fffu + ((u >> 16) & 1u);
    return (unsigned short)(u >> 16);
}
static __device__ __forceinline__ float bf16f(unsigned short h) {
    return __uint_as_float((unsigned int)h << 16);
}

__global__ __launch_bounds__(THREADS)
void dct_kernel(const float* __restrict__ x,
                const float* __restrict__ Kmat,
                float* __restrict__ out,
                int nt) {
    __shared__ short bhi[8 * 64 * 8];   // 8 KB  [combo][lane][j]
    __shared__ short blo[8 * 64 * 8];   // 8 KB

    const int tid  = threadIdx.x;
    const int lane = tid & 63;
    const int wv   = tid >> 6;          // 0..3
    const int l15  = lane & 15;
    const int quad = lane >> 4;         // 0..3

    const int totw = (int)gridDim.x * WPB;              // total waves
    const long long wt0 = (long long)blockIdx.x * WPB + wv;
    const float* src = x + (wt0 * 16 + l15) * 64 + quad * 8;
    float* dst = out + wt0 * 1024;
    const long long SSTEP = (long long)totw * 1024;     // floats between a wave's tiles

    // ---- issue tile-0 loads FIRST: HBM latency hides under K build ----
    float4 c0, c1, c2, c3;
    if (wt0 < nt) {
        c0 = *(const float4*)(src);
        c1 = *(const float4*)(src + 4);
        c2 = *(const float4*)(src + 32);
        c3 = *(const float4*)(src + 36);
    }

    // ---- build K bf16 hi/lo B-frags once; wave wv builds combos 2wv,2wv+1 --
    // combo = kc*4 + ft ; lane holds B[k = kc*32+quad*8+j][n = ft*16+l15]
#pragma unroll
    for (int cc = 0; cc < 2; ++cc) {
        const int combo = wv * 2 + cc;
        const int kc = combo >> 2, ft = combo & 3;
        short hh[8], ll[8];
#pragma unroll
        for (int j = 0; j < 8; ++j) {
            float v = Kmat[(kc * 32 + quad * 8 + j) * 64 + ft * 16 + l15];
            unsigned short h = bf16_rne(v);
            hh[j] = (short)h;
            ll[j] = (short)bf16_rne(v - bf16f(h));
        }
        *(bf16x8*)&bhi[(combo * 64 + lane) * 8] = *(bf16x8*)hh;  // lane-linear 16B
        *(bf16x8*)&blo[(combo * 64 + lane) * 8] = *(bf16x8*)ll;
    }
    __syncthreads();

    // ---- hoist all 16 B-frags to registers (64 VGPR); LDS done after this --
    bf16x8 Bh[8], Bl[8];
#pragma unroll
    for (int c = 0; c < 8; ++c) {
        Bh[c] = *(const bf16x8*)&bhi[(c * 64 + lane) * 8];
        Bl[c] = *(const bf16x8*)&blo[(c * 64 + lane) * 8];
    }

    // ---- streaming main loop: prefetch next tile, compute current ----
#pragma unroll
    for (int s = 0; s < TPW; ++s) {
        if (wt0 + (long long)s * totw >= nt) break;

        float4 n0, n1, n2, n3;
        const bool more = (s + 1 < TPW) && (wt0 + (long long)(s + 1) * totw < nt);
        if (more) {
            const float* ns = src + (long long)(s + 1) * SSTEP;
            n0 = *(const float4*)(ns);
            n1 = *(const float4*)(ns + 4);
            n2 = *(const float4*)(ns + 32);
            n3 = *(const float4*)(ns + 36);
        }

        f32x4 acc[4];
#pragma unroll
        for (int t = 0; t < 4; ++t) acc[t] = (f32x4){0.f, 0.f, 0.f, 0.f};

#pragma unroll
        for (int kc = 0; kc < 2; ++kc) {
            float av[8];
            *(float4*)&av[0] = kc ? c2 : c0;
            *(float4*)&av[4] = kc ? c3 : c1;
            short ah[8], al[8];
#pragma unroll
            for (int j = 0; j < 8; ++j) {
                unsigned short h = bf16_rne(av[j]);
                ah[j] = (short)h;
                al[j] = (short)bf16_rne(av[j] - bf16f(h));
            }
            bf16x8 Ahi = *(bf16x8*)ah;
            bf16x8 Alo = *(bf16x8*)al;
#pragma unroll
            for (int ft = 0; ft < 4; ++ft) {
                const int c = kc * 4 + ft;
                acc[ft] = __builtin_amdgcn_mfma_f32_16x16x32_bf16(Ahi, Bh[c], acc[ft], 0, 0, 0);
                acc[ft] = __builtin_amdgcn_mfma_f32_16x16x32_bf16(Alo, Bh[c], acc[ft], 0, 0, 0);
                acc[ft] = __builtin_amdgcn_mfma_f32_16x16x32_bf16(Ahi, Bl[c], acc[ft], 0, 0, 0);
            }
        }

        // epilogue: C/D layout col=l15, row=quad*4+r; 4x64B segments / instr
        float* ob = dst + (long long)s * SSTEP;
#pragma unroll
        for (int ft = 0; ft < 4; ++ft)
#pragma unroll
            for (int r = 0; r < 4; ++r)
                ob[(quad * 4 + r) * 64 + ft * 16 + l15] = acc[ft][r];

        if (more) { c0 = n0; c1 = n1; c2 = n2; c3 = n3; }
    }
}

extern "C" void kernel_launch(void* const* d_in, const int* in_sizes, int n_in,
                              void* d_out, int out_size, void* d_ws, size_t ws_size,
                              hipStream_t stream) {
    const float* x = (const float*)d_in[0];   // (8,3,1024,1024) fp32
    const float* K = (const float*)d_in[1];   // (64,64) fp32
    float* out = (float*)d_out;

    const int total = in_sizes[0];            // 25,165,824 floats
    const int num_patches = total / 64;       // 393,216
    const int wave_tiles  = num_patches / 16; // 24,576
    const int blocks = (wave_tiles + WPB * TPW - 1) / (WPB * TPW);  // 2048

    dct_kernel<<<blocks, THREADS, 0, stream>>>(x, K, out, wave_tiles);
}